// Round 6
// baseline (354.679 us; speedup 1.0000x reference)
//
#include <hip/hip_runtime.h>

#define NQ 12
#define NL 6
#define NC 10
#define DIM 4096
#define TPB 512
#define NPASS 24

typedef float v2f __attribute__((ext_vector_type(2)));
#define FMA2(a, b, c) __builtin_elementwise_fma((a), (b), (c))

__device__ __forceinline__ v2f splat2(float v) { v2f r; r.x = v; r.y = v; return r; }

// VOP3P packed-f32, coefficient broadcast via op_sel.
// P is a v2f coefficient pair; _L broadcasts its lo 32b to both halves, _H its hi 32b.
#define PKMUL_L(d, P, B) asm("v_pk_mul_f32 %0, %1, %2 op_sel:[0,0] op_sel_hi:[0,1]" : "=v"(d) : "v"(P), "v"(B))
#define PKMUL_H(d, P, B) asm("v_pk_mul_f32 %0, %1, %2 op_sel:[1,0] op_sel_hi:[1,1]" : "=v"(d) : "v"(P), "v"(B))
#define PKFMA_L(d, P, B, C) asm("v_pk_fma_f32 %0, %1, %2, %3 op_sel:[0,0,0] op_sel_hi:[0,1,1]" : "=v"(d) : "v"(P), "v"(B), "v"(C))
#define PKFMA_H(d, P, B, C) asm("v_pk_fma_f32 %0, %1, %2, %3 op_sel:[1,0,0] op_sel_hi:[1,1,1]" : "=v"(d) : "v"(P), "v"(B), "v"(C))

struct PassA { unsigned short Acol[9]; unsigned short svo4[8]; unsigned short w[3]; };
struct QCArgs {
    PassA P[NPASS];
    unsigned short Gcol0[9];
    unsigned short vc0[8];
    unsigned short wq[NQ];
    unsigned char  tab[NQ];
};

__global__ __launch_bounds__(TPB, 4) void qsim_k(
    const float* __restrict__ x, const float* __restrict__ qp,
    const float* __restrict__ fcw, const float* __restrict__ fcb,
    float* __restrict__ out, int B, QCArgs K)
{
    __shared__ float4 stv[DIM];          // (re.b0, re.b1, im.b0, im.b1), layout T*m
    __shared__ float4 gmat[NL * NQ];     // (ur, ui, wr, wi)
    __shared__ v2f csn[NQ], snn[NQ];
    __shared__ v2f zred[8 * NQ];
    __shared__ v2f zfin[NQ];

    const unsigned tid = threadIdx.x;
    const int blk = blockIdx.x;
    const int b0 = blk * 2;
    const int b1 = blk * 2 + 1;

    if (tid < NL * NQ) {
        float phi = qp[tid * 3 + 0];
        float th  = qp[tid * 3 + 1];
        float om  = qp[tid * 3 + 2];
        float st_, ct, sa, ca, sb, cb;
        sincosf(0.5f * th, &st_, &ct);
        sincosf(0.5f * (phi + om), &sa, &ca);
        sincosf(0.5f * (phi - om), &sb, &cb);
        gmat[tid] = make_float4(ca * ct, -sa * ct, cb * st_, -sb * st_);
    }
    if (tid < 2 * NQ) {
        int half = tid / NQ;
        int q = tid - half * NQ;
        int bb = blk * 2 + half;
        float xx = (bb < B) ? x[bb * NQ + q] : 0.0f;
        float s, c;
        sincosf(0.5f * xx, &s, &c);
        if (half == 0) { csn[q].x = c; snn[q].x = s; }
        else           { csn[q].y = c; snn[q].y = s; }
    }
    __syncthreads();

    v2f aR[8], aI[8];

    #pragma unroll 1
    for (int k = 0; k < NPASS; ++k) {
        const PassA& P = K.P[k];
        unsigned A = 0;
        #pragma unroll
        for (int b2 = 0; b2 < 9; ++b2)
            A ^= ((tid >> b2) & 1u) ? (unsigned)P.Acol[b2] : 0u;
        unsigned ad[8];
        #pragma unroll
        for (int s = 0; s < 8; ++s) ad[s] = A ^ (unsigned)P.svo4[s];

        if (k == 0) {
            // initial product state directly in registers (no LDS round-trip)
            unsigned G = 0;
            #pragma unroll
            for (int b2 = 0; b2 < 9; ++b2)
                G ^= ((tid >> b2) & 1u) ? (unsigned)K.Gcol0[b2] : 0u;
            #pragma unroll
            for (int s = 0; s < 8; ++s) {
                unsigned idx = G ^ (unsigned)K.vc0[s];
                v2f amp = splat2(1.0f);
                #pragma unroll
                for (int p = 0; p < 12; ++p)
                    amp *= ((idx >> p) & 1) ? snn[11 - p] : csn[11 - p];
                aR[s] = amp;
                aI[s] = splat2(0.0f);
            }
        } else {
            __syncthreads();
            #pragma unroll
            for (int s = 0; s < 8; ++s) {
                float4 f4 = *(const float4*)((const char*)stv + ad[s]);
                aR[s].x = f4.x; aR[s].y = f4.y;
                aI[s].x = f4.z; aI[s].y = f4.w;
            }
        }

        const int gb = (k >> 2) * NQ + (k & 3) * 3;
        #pragma unroll
        for (int j = 0; j < 3; ++j) {
            float4 gq = gmat[gb + j];
            unsigned sg = (unsigned)(__popc((unsigned)P.w[j] & tid) & 1) << 31;
            v2f P1, P1n, P2, P2n;
            P1.x  = gq.x;
            P1.y  = __uint_as_float(__float_as_uint(gq.y) ^ sg);
            P1n.x = gq.x;
            P1n.y = __uint_as_float(__float_as_uint(P1.y) ^ 0x80000000u);
            P2.x  = __uint_as_float(__float_as_uint(gq.z) ^ sg);
            P2.y  = gq.w;
            P2n.x = __uint_as_float(__float_as_uint(P2.x) ^ 0x80000000u);
            P2n.y = __uint_as_float(__float_as_uint(gq.w) ^ 0x80000000u);
            #pragma unroll
            for (int s = 0; s < 8; ++s) {
                if (!(s & (1 << j))) {
                    const int sb = s | (1 << j);
                    v2f a0r = aR[s], a0i = aI[s], a1r = aR[sb], a1i = aI[sb];
                    v2f t, o;
                    // o0r = ur*a0r - u1*a0i - w1*a1r - wi*a1i
                    PKMUL_H(t, P2n, a1i); PKFMA_L(t, P2n, a1r, t); PKFMA_H(t, P1n, a0i, t); PKFMA_L(o, P1, a0r, t); aR[s] = o;
                    // o0i = ur*a0i + u1*a0r - w1*a1i + wi*a1r
                    PKMUL_H(t, P2, a1r);  PKFMA_L(t, P2n, a1i, t); PKFMA_H(t, P1, a0r, t);  PKFMA_L(o, P1, a0i, t); aI[s] = o;
                    // o1r = ur*a1r + u1*a1i + w1*a0r - wi*a0i
                    PKMUL_H(t, P2n, a0i); PKFMA_L(t, P2, a0r, t);  PKFMA_H(t, P1, a1i, t);  PKFMA_L(o, P1, a1r, t); aR[sb] = o;
                    // o1i = ur*a1i - u1*a1r + w1*a0i + wi*a0r
                    PKMUL_H(t, P2, a0r);  PKFMA_L(t, P2, a0i, t);  PKFMA_H(t, P1n, a1r, t); PKFMA_L(o, P1, a1i, t); aI[sb] = o;
                }
            }
        }

        if (k < NPASS - 1) {
            #pragma unroll
            for (int s = 0; s < 8; ++s)
                *(float4*)((char*)stv + ad[s]) =
                    make_float4(aR[s].x, aR[s].y, aI[s].x, aI[s].y);
        }
    }

    // ---- PauliZ expvals from final-pass registers ----
    v2f p2[8];
    #pragma unroll
    for (int s = 0; s < 8; ++s) p2[s] = FMA2(aR[s], aR[s], aI[s] * aI[s]);

    v2f z[NQ];
    #pragma unroll
    for (int q = 0; q < NQ; ++q) {
        float base = (__popc((unsigned)K.wq[q] & tid) & 1) ? -1.0f : 1.0f;
        v2f acc = splat2(0.0f);
        #pragma unroll
        for (int s = 0; s < 8; ++s) {
            float sgn = ((K.tab[q] >> s) & 1) ? -base : base;
            acc = FMA2(splat2(sgn), p2[s], acc);
        }
        z[q] = acc;
    }

    #pragma unroll
    for (int q = 0; q < NQ; ++q) {
        float vx = z[q].x, vy = z[q].y;
        #pragma unroll
        for (int o = 1; o < 64; o <<= 1) {
            vx += __shfl_xor(vx, o, 64);
            vy += __shfl_xor(vy, o, 64);
        }
        z[q].x = vx; z[q].y = vy;
    }
    const int lane = tid & 63, wv = tid >> 6;
    if (lane == 0) {
        #pragma unroll
        for (int q = 0; q < NQ; ++q) zred[wv * NQ + q] = z[q];
    }
    __syncthreads();
    if (tid < NQ) {
        v2f acc = zred[tid];
        #pragma unroll
        for (int w2 = 1; w2 < 8; ++w2) acc += zred[w2 * NQ + tid];
        zfin[tid] = acc;
    }
    __syncthreads();

    if (tid < NC) {
        v2f acc = splat2(fcb[tid]);
        #pragma unroll
        for (int q = 0; q < NQ; ++q) acc = FMA2(splat2(fcw[tid * NQ + q]), zfin[q], acc);
        out[b0 * NC + tid] = acc.x;
        if (b1 < B) out[b1 * NC + tid] = acc.y;
    }
}

// ---------------- host: GF(2) circuit algebra + per-8-lane conflict-free layout ----------------
static void inv12(const unsigned Ain[12], unsigned Ai[12]) {
    unsigned M[12], I[12];
    for (int i = 0; i < 12; ++i) { M[i] = Ain[i]; I[i] = 1u << i; }
    for (int c = 0; c < 12; ++c) {
        int pr = -1;
        for (int r2 = c; r2 < 12; ++r2) if ((M[r2] >> c) & 1u) { pr = r2; break; }
        unsigned tm = M[c]; M[c] = M[pr]; M[pr] = tm;
        tm = I[c]; I[c] = I[pr]; I[pr] = tm;
        for (int r2 = 0; r2 < 12; ++r2)
            if (r2 != c && ((M[r2] >> c) & 1u)) { M[r2] ^= M[c]; I[r2] ^= I[c]; }
    }
    for (int i = 0; i < 12; ++i) Ai[i] = I[i];
}

static unsigned lcg(unsigned& s) { s = s * 1664525u + 1013904223u; return s >> 8; }
static int pc(unsigned v) { return __builtin_popcount(v); }

static int rank_rows(const unsigned* rows, int n) {
    unsigned ech[16], low[16]; int rk = 0;
    for (int i = 0; i < n; ++i) {
        unsigned v = rows[i];
        for (int k2 = 0; k2 < rk; ++k2) if (v & low[k2]) v ^= ech[k2];
        if (v) { ech[rk] = v; low[rk] = v & (0u - v); ++rk; }
    }
    return rk;
}

extern "C" void kernel_launch(void* const* d_in, const int* in_sizes, int n_in,
                              void* d_out, int out_size, void* d_ws, size_t ws_size,
                              hipStream_t stream) {
    const float* x    = (const float*)d_in[0];
    const float* qp   = (const float*)d_in[1];
    const float* fc_w = (const float*)d_in[2];
    const float* fc_b = (const float*)d_in[3];
    float* out = (float*)d_out;
    int B = in_sizes[0] / NQ;

    unsigned L[12];
    for (int i = 0; i < 12; ++i) L[i] = 1u << i;

    static unsigned vAll[NPASS][3], rAll[NPASS][3], vcAll[NPASS][8];
    static int posAll[NPASS][9];

    for (int l = 0; l < NL; ++l) {
        unsigned Linv[12];
        inv12(L, Linv);
        for (int m = 0; m < 4; ++m) {
            int k = l * 4 + m;
            for (int j = 0; j < 3; ++j) {
                int q = 3 * m + j, bb = 11 - q;
                rAll[k][j] = L[bb];
                unsigned vv = 0;
                for (int i = 0; i < 12; ++i) vv |= ((Linv[i] >> bb) & 1u) << i;
                vAll[k][j] = vv;
            }
            unsigned w[3] = { vAll[k][0], vAll[k][1], vAll[k][2] };
            int piv[3];
            for (int j = 0; j < 3; ++j) {
                for (int k2 = 0; k2 < j; ++k2)
                    if ((w[j] >> piv[k2]) & 1u) w[j] ^= w[k2];
                piv[j] = __builtin_ctz(w[j]);
            }
            bool ispiv[12] = {};
            for (int j = 0; j < 3; ++j) ispiv[piv[j]] = true;
            int c = 0;
            for (int pos = 0; pos < 12; ++pos)
                if (!ispiv[pos]) posAll[k][c++] = pos;
            for (int s = 0; s < 8; ++s) {
                unsigned vc = 0;
                for (int j = 0; j < 3; ++j) if ((s >> j) & 1) vc ^= vAll[k][j];
                vcAll[k][s] = vc;
            }
        }
        int rr = l + 1;
        for (int q = 0; q < 12; ++q) {
            int tq = (q + rr) % 12;
            L[11 - tq] ^= L[11 - q];
        }
    }
    unsigned rfin[12];
    for (int q = 0; q < 12; ++q) rfin[q] = L[11 - q];

    // ---- label search: nonzero 3-bit label per position; every pass's 9 positions must span GF(2)^3 ----
    unsigned labels[12];
    unsigned seed = 0xC0FFEE1u;
    bool okL = false;
    for (int att = 0; att < 300000 && !okL; ++att) {
        for (int i = 0; i < 12; ++i) labels[i] = 1u + (lcg(seed) % 7u);
        okL = true;
        for (int k = 0; k < NPASS && okL; ++k) {
            unsigned vals[9];
            for (int b = 0; b < 9; ++b) vals[b] = labels[posAll[k][b]];
            okL = (rank_rows(vals, 9) >= 3);
        }
    }

    // ---- per-pass: move an independent-label triple to thread bits 0..2 ----
    for (int k = 0; k < NPASS; ++k) {
        int used[9] = {};
        int chosen[3]; int nch = 0;
        unsigned ech[3], low[3]; int rk = 0;
        for (int b = 0; b < 9 && nch < 3; ++b) {
            unsigned v = labels[posAll[k][b]];
            for (int j = 0; j < rk; ++j) if (v & low[j]) v ^= ech[j];
            if (v) { ech[rk] = v; low[rk] = v & (0u - v); ++rk; chosen[nch++] = b; used[b] = 1; }
        }
        for (int b = 0; b < 9 && nch < 3; ++b)
            if (!used[b]) { chosen[nch++] = b; used[b] = 1; }
        int outp[9]; int c2 = 0;
        for (int j = 0; j < nch; ++j) outp[c2++] = posAll[k][chosen[j]];
        for (int b = 0; b < 9; ++b) if (!used[b]) outp[c2++] = posAll[k][b];
        for (int b = 0; b < 9; ++b) posAll[k][b] = outp[b];
    }

    // ---- layout matrix T: rows 0..2 from labels, extend to full rank ----
    unsigned Trow[12];
    for (int i = 0; i < 3; ++i) {
        unsigned r = 0;
        for (int pos = 0; pos < 12; ++pos) r |= ((labels[pos] >> i) & 1u) << pos;
        Trow[i] = r;
    }
    {
        unsigned ech[12], low[12]; int rk = 0;
        auto addrow = [&](unsigned vr) -> bool {
            unsigned vv = vr;
            for (int i = 0; i < rk; ++i) if (vv & low[i]) vv ^= ech[i];
            if (!vv) return false;
            ech[rk] = vv; low[rk] = vv & (0u - vv); ++rk;
            return true;
        };
        addrow(Trow[0]); addrow(Trow[1]); addrow(Trow[2]);
        int idx = 3, tries = 0;
        while (idx < 12 && tries < 100000) {
            unsigned rr2 = lcg(seed) & 4095u;
            if (rr2 && addrow(rr2)) Trow[idx++] = rr2;
            ++tries;
        }
        for (int i = 0; i < 12 && idx < 12; ++i)
            if (addrow(1u << i)) Trow[idx++] = 1u << i;
    }
    unsigned Tcol[12];
    for (int pos = 0; pos < 12; ++pos) {
        unsigned o = 0;
        for (int i = 0; i < 12; ++i) o |= ((Trow[i] >> pos) & 1u) << i;
        Tcol[pos] = o;
    }
    auto Tmap = [&](unsigned m) -> unsigned {
        unsigned o = 0;
        for (int i = 0; i < 12; ++i) o |= (unsigned)(pc(Trow[i] & m) & 1) << i;
        return o;
    };

    QCArgs K;
    for (int k = 0; k < NPASS; ++k) {
        for (int b = 0; b < 9; ++b)
            K.P[k].Acol[b] = (unsigned short)(Tcol[posAll[k][b]] << 4);
        for (int s = 0; s < 8; ++s)
            K.P[k].svo4[s] = (unsigned short)(Tmap(vcAll[k][s]) << 4);
        for (int j = 0; j < 3; ++j) {
            unsigned ws = 0;
            for (int b = 0; b < 9; ++b)
                ws |= ((rAll[k][j] >> posAll[k][b]) & 1u) << b;
            K.P[k].w[j] = (unsigned short)ws;
        }
    }
    for (int b = 0; b < 9; ++b) K.Gcol0[b] = (unsigned short)(1u << posAll[0][b]);
    for (int s = 0; s < 8; ++s) K.vc0[s] = (unsigned short)vcAll[0][s];
    for (int q = 0; q < NQ; ++q) {
        unsigned ws = 0;
        for (int b = 0; b < 9; ++b)
            ws |= ((rfin[q] >> posAll[NPASS - 1][b]) & 1u) << b;
        K.wq[q] = (unsigned short)ws;
        unsigned tb = 0;
        for (int s = 0; s < 8; ++s)
            tb |= (unsigned)(pc(rfin[q] & vcAll[NPASS - 1][s]) & 1) << s;
        K.tab[q] = (unsigned char)tb;
    }

    int nblk = (B + 1) / 2;
    qsim_k<<<nblk, TPB, 0, stream>>>(x, qp, fc_w, fc_b, out, B, K);
}

// Round 7
// 351.410 us; speedup vs baseline: 1.0093x; 1.0093x over previous
//
#include <hip/hip_runtime.h>

#define NQ 12
#define NL 6
#define NC 10
#define DIM 4096
#define TPB 512
#define NPASS 24

typedef float v2f __attribute__((ext_vector_type(2)));
#define FMA2(a, b, c) __builtin_elementwise_fma((a), (b), (c))

__device__ __forceinline__ v2f splat2(float v) { v2f r; r.x = v; r.y = v; return r; }

struct PassA { unsigned short Acol[9]; unsigned short svo4[8]; unsigned short w[3]; };
struct QCArgs {
    PassA P[NPASS];
    unsigned short Gcol0[9];
    unsigned short vc0[8];
    unsigned short wq[NQ];
    unsigned char  tab[NQ];
};

__global__ __launch_bounds__(TPB, 4) void qsim_k(
    const float* __restrict__ x, const float* __restrict__ qp,
    const float* __restrict__ fcw, const float* __restrict__ fcb,
    float* __restrict__ out, int B, QCArgs K)
{
    __shared__ float4 stv[DIM];          // (re.b0, re.b1, im.b0, im.b1), layout T*m
    __shared__ float4 gmat[NL * NQ];     // (ur, ui, wr, wi)
    __shared__ v2f csn[NQ], snn[NQ];
    __shared__ v2f zred[8 * NQ];
    __shared__ v2f zfin[NQ];

    const unsigned tid = threadIdx.x;
    const int blk = blockIdx.x;
    const int b0 = blk * 2;
    const int b1 = blk * 2 + 1;

    if (tid < NL * NQ) {
        float phi = qp[tid * 3 + 0];
        float th  = qp[tid * 3 + 1];
        float om  = qp[tid * 3 + 2];
        float st_, ct, sa, ca, sb, cb;
        sincosf(0.5f * th, &st_, &ct);
        sincosf(0.5f * (phi + om), &sa, &ca);
        sincosf(0.5f * (phi - om), &sb, &cb);
        gmat[tid] = make_float4(ca * ct, -sa * ct, cb * st_, -sb * st_);
    }
    if (tid < 2 * NQ) {
        int half = tid / NQ;
        int q = tid - half * NQ;
        int bb = blk * 2 + half;
        float xx = (bb < B) ? x[bb * NQ + q] : 0.0f;
        float s, c;
        sincosf(0.5f * xx, &s, &c);
        if (half == 0) { csn[q].x = c; snn[q].x = s; }
        else           { csn[q].y = c; snn[q].y = s; }
    }
    __syncthreads();

    v2f aR[8], aI[8];

    #pragma unroll 1
    for (int k = 0; k < NPASS; ++k) {
        const PassA& P = K.P[k];
        unsigned A = 0;
        #pragma unroll
        for (int b2 = 0; b2 < 9; ++b2)
            A ^= ((tid >> b2) & 1u) ? (unsigned)P.Acol[b2] : 0u;
        unsigned ad[8];
        #pragma unroll
        for (int s = 0; s < 8; ++s) ad[s] = A ^ (unsigned)P.svo4[s];

        if (k == 0) {
            // initial product state directly in registers (no LDS round-trip)
            unsigned G = 0;
            #pragma unroll
            for (int b2 = 0; b2 < 9; ++b2)
                G ^= ((tid >> b2) & 1u) ? (unsigned)K.Gcol0[b2] : 0u;
            #pragma unroll
            for (int s = 0; s < 8; ++s) {
                unsigned idx = G ^ (unsigned)K.vc0[s];
                v2f amp = splat2(1.0f);
                #pragma unroll
                for (int p = 0; p < 12; ++p)
                    amp *= ((idx >> p) & 1) ? snn[11 - p] : csn[11 - p];
                aR[s] = amp;
                aI[s] = splat2(0.0f);
            }
        } else {
            __syncthreads();
            #pragma unroll
            for (int s = 0; s < 8; ++s) {
                float4 f4 = *(const float4*)((const char*)stv + ad[s]);
                aR[s].x = f4.x; aR[s].y = f4.y;
                aI[s].x = f4.z; aI[s].y = f4.w;
            }
        }

        const int gb = (k >> 2) * NQ + (k & 3) * 3;
        #pragma unroll
        for (int j = 0; j < 3; ++j) {
            float4 gq = gmat[gb + j];
            unsigned sg = (unsigned)(__popc((unsigned)P.w[j] & tid) & 1) << 31;
            float uia = __uint_as_float(__float_as_uint(gq.y) ^ sg);
            float wra = __uint_as_float(__float_as_uint(gq.z) ^ sg ^ 0x80000000u);
            const v2f ur2  = splat2(gq.x);
            const v2f uia2 = splat2(uia);
            const v2f wra2 = splat2(wra);
            const v2f wi2  = splat2(gq.w);
            #pragma unroll
            for (int s = 0; s < 8; ++s) {
                if (!(s & (1 << j))) {
                    const int sb = s | (1 << j);
                    v2f a0r = aR[s],  a0i = aI[s];
                    v2f a1r = aR[sb], a1i = aI[sb];
                    aR[s]  = FMA2(ur2, a0r, FMA2(-uia2, a0i, FMA2(wra2, a1r, -wi2 * a1i)));
                    aI[s]  = FMA2(ur2, a0i, FMA2(uia2,  a0r, FMA2(wra2, a1i,  wi2 * a1r)));
                    aR[sb] = FMA2(ur2, a1r, FMA2(uia2,  a1i, FMA2(-wra2, a0r, -wi2 * a0i)));
                    aI[sb] = FMA2(ur2, a1i, FMA2(-uia2, a1r, FMA2(-wra2, a0i,  wi2 * a0r)));
                }
            }
        }

        if (k < NPASS - 1) {
            #pragma unroll
            for (int s = 0; s < 8; ++s)
                *(float4*)((char*)stv + ad[s]) =
                    make_float4(aR[s].x, aR[s].y, aI[s].x, aI[s].y);
        }
    }

    // ---- PauliZ expvals from final-pass registers ----
    v2f p2[8];
    #pragma unroll
    for (int s = 0; s < 8; ++s) p2[s] = FMA2(aR[s], aR[s], aI[s] * aI[s]);

    v2f z[NQ];
    #pragma unroll
    for (int q = 0; q < NQ; ++q) {
        float base = (__popc((unsigned)K.wq[q] & tid) & 1) ? -1.0f : 1.0f;
        v2f acc = splat2(0.0f);
        #pragma unroll
        for (int s = 0; s < 8; ++s) {
            float sgn = ((K.tab[q] >> s) & 1) ? -base : base;
            acc = FMA2(splat2(sgn), p2[s], acc);
        }
        z[q] = acc;
    }

    #pragma unroll
    for (int q = 0; q < NQ; ++q) {
        float vx = z[q].x, vy = z[q].y;
        #pragma unroll
        for (int o = 1; o < 64; o <<= 1) {
            vx += __shfl_xor(vx, o, 64);
            vy += __shfl_xor(vy, o, 64);
        }
        z[q].x = vx; z[q].y = vy;
    }
    const int lane = tid & 63, wv = tid >> 6;
    if (lane == 0) {
        #pragma unroll
        for (int q = 0; q < NQ; ++q) zred[wv * NQ + q] = z[q];
    }
    __syncthreads();
    if (tid < NQ) {
        v2f acc = zred[tid];
        #pragma unroll
        for (int w2 = 1; w2 < 8; ++w2) acc += zred[w2 * NQ + tid];
        zfin[tid] = acc;
    }
    __syncthreads();

    if (tid < NC) {
        v2f acc = splat2(fcb[tid]);
        #pragma unroll
        for (int q = 0; q < NQ; ++q) acc = FMA2(splat2(fcw[tid * NQ + q]), zfin[q], acc);
        out[b0 * NC + tid] = acc.x;
        if (b1 < B) out[b1 * NC + tid] = acc.y;
    }
}

// ---------------- host: GF(2) circuit algebra + per-8-lane conflict-free layout ----------------
static void inv12(const unsigned Ain[12], unsigned Ai[12]) {
    unsigned M[12], I[12];
    for (int i = 0; i < 12; ++i) { M[i] = Ain[i]; I[i] = 1u << i; }
    for (int c = 0; c < 12; ++c) {
        int pr = -1;
        for (int r2 = c; r2 < 12; ++r2) if ((M[r2] >> c) & 1u) { pr = r2; break; }
        unsigned tm = M[c]; M[c] = M[pr]; M[pr] = tm;
        tm = I[c]; I[c] = I[pr]; I[pr] = tm;
        for (int r2 = 0; r2 < 12; ++r2)
            if (r2 != c && ((M[r2] >> c) & 1u)) { M[r2] ^= M[c]; I[r2] ^= I[c]; }
    }
    for (int i = 0; i < 12; ++i) Ai[i] = I[i];
}

static unsigned lcg(unsigned& s) { s = s * 1664525u + 1013904223u; return s >> 8; }
static int pc(unsigned v) { return __builtin_popcount(v); }

static int rank_rows(const unsigned* rows, int n) {
    unsigned ech[16], low[16]; int rk = 0;
    for (int i = 0; i < n; ++i) {
        unsigned v = rows[i];
        for (int k2 = 0; k2 < rk; ++k2) if (v & low[k2]) v ^= ech[k2];
        if (v) { ech[rk] = v; low[rk] = v & (0u - v); ++rk; }
    }
    return rk;
}

extern "C" void kernel_launch(void* const* d_in, const int* in_sizes, int n_in,
                              void* d_out, int out_size, void* d_ws, size_t ws_size,
                              hipStream_t stream) {
    const float* x    = (const float*)d_in[0];
    const float* qp   = (const float*)d_in[1];
    const float* fc_w = (const float*)d_in[2];
    const float* fc_b = (const float*)d_in[3];
    float* out = (float*)d_out;
    int B = in_sizes[0] / NQ;

    unsigned L[12];
    for (int i = 0; i < 12; ++i) L[i] = 1u << i;

    static unsigned vAll[NPASS][3], rAll[NPASS][3], vcAll[NPASS][8];
    static int posAll[NPASS][9];

    for (int l = 0; l < NL; ++l) {
        unsigned Linv[12];
        inv12(L, Linv);
        for (int m = 0; m < 4; ++m) {
            int k = l * 4 + m;
            for (int j = 0; j < 3; ++j) {
                int q = 3 * m + j, bb = 11 - q;
                rAll[k][j] = L[bb];
                unsigned vv = 0;
                for (int i = 0; i < 12; ++i) vv |= ((Linv[i] >> bb) & 1u) << i;
                vAll[k][j] = vv;
            }
            unsigned w[3] = { vAll[k][0], vAll[k][1], vAll[k][2] };
            int piv[3];
            for (int j = 0; j < 3; ++j) {
                for (int k2 = 0; k2 < j; ++k2)
                    if ((w[j] >> piv[k2]) & 1u) w[j] ^= w[k2];
                piv[j] = __builtin_ctz(w[j]);
            }
            bool ispiv[12] = {};
            for (int j = 0; j < 3; ++j) ispiv[piv[j]] = true;
            int c = 0;
            for (int pos = 0; pos < 12; ++pos)
                if (!ispiv[pos]) posAll[k][c++] = pos;
            for (int s = 0; s < 8; ++s) {
                unsigned vc = 0;
                for (int j = 0; j < 3; ++j) if ((s >> j) & 1) vc ^= vAll[k][j];
                vcAll[k][s] = vc;
            }
        }
        int rr = l + 1;
        for (int q = 0; q < 12; ++q) {
            int tq = (q + rr) % 12;
            L[11 - tq] ^= L[11 - q];
        }
    }
    unsigned rfin[12];
    for (int q = 0; q < 12; ++q) rfin[q] = L[11 - q];

    // ---- label search: nonzero 3-bit label per position; every pass's 9 positions must span GF(2)^3 ----
    unsigned labels[12];
    unsigned seed = 0xC0FFEE1u;
    bool okL = false;
    for (int att = 0; att < 300000 && !okL; ++att) {
        for (int i = 0; i < 12; ++i) labels[i] = 1u + (lcg(seed) % 7u);
        okL = true;
        for (int k = 0; k < NPASS && okL; ++k) {
            unsigned vals[9];
            for (int b = 0; b < 9; ++b) vals[b] = labels[posAll[k][b]];
            okL = (rank_rows(vals, 9) >= 3);
        }
    }

    // ---- per-pass: move an independent-label triple to thread bits 0..2 ----
    for (int k = 0; k < NPASS; ++k) {
        int used[9] = {};
        int chosen[3]; int nch = 0;
        unsigned ech[3], low[3]; int rk = 0;
        for (int b = 0; b < 9 && nch < 3; ++b) {
            unsigned v = labels[posAll[k][b]];
            for (int j = 0; j < rk; ++j) if (v & low[j]) v ^= ech[j];
            if (v) { ech[rk] = v; low[rk] = v & (0u - v); ++rk; chosen[nch++] = b; used[b] = 1; }
        }
        for (int b = 0; b < 9 && nch < 3; ++b)
            if (!used[b]) { chosen[nch++] = b; used[b] = 1; }
        int outp[9]; int c2 = 0;
        for (int j = 0; j < nch; ++j) outp[c2++] = posAll[k][chosen[j]];
        for (int b = 0; b < 9; ++b) if (!used[b]) outp[c2++] = posAll[k][b];
        for (int b = 0; b < 9; ++b) posAll[k][b] = outp[b];
    }

    // ---- layout matrix T: rows 0..2 from labels, extend to full rank ----
    unsigned Trow[12];
    for (int i = 0; i < 3; ++i) {
        unsigned r = 0;
        for (int pos = 0; pos < 12; ++pos) r |= ((labels[pos] >> i) & 1u) << pos;
        Trow[i] = r;
    }
    {
        unsigned ech[12], low[12]; int rk = 0;
        auto addrow = [&](unsigned vr) -> bool {
            unsigned vv = vr;
            for (int i = 0; i < rk; ++i) if (vv & low[i]) vv ^= ech[i];
            if (!vv) return false;
            ech[rk] = vv; low[rk] = vv & (0u - vv); ++rk;
            return true;
        };
        addrow(Trow[0]); addrow(Trow[1]); addrow(Trow[2]);
        int idx = 3, tries = 0;
        while (idx < 12 && tries < 100000) {
            unsigned rr2 = lcg(seed) & 4095u;
            if (rr2 && addrow(rr2)) Trow[idx++] = rr2;
            ++tries;
        }
        for (int i = 0; i < 12 && idx < 12; ++i)
            if (addrow(1u << i)) Trow[idx++] = 1u << i;
    }
    unsigned Tcol[12];
    for (int pos = 0; pos < 12; ++pos) {
        unsigned o = 0;
        for (int i = 0; i < 12; ++i) o |= ((Trow[i] >> pos) & 1u) << i;
        Tcol[pos] = o;
    }
    auto Tmap = [&](unsigned m) -> unsigned {
        unsigned o = 0;
        for (int i = 0; i < 12; ++i) o |= (unsigned)(pc(Trow[i] & m) & 1) << i;
        return o;
    };

    QCArgs K;
    for (int k = 0; k < NPASS; ++k) {
        for (int b = 0; b < 9; ++b)
            K.P[k].Acol[b] = (unsigned short)(Tcol[posAll[k][b]] << 4);
        for (int s = 0; s < 8; ++s)
            K.P[k].svo4[s] = (unsigned short)(Tmap(vcAll[k][s]) << 4);
        for (int j = 0; j < 3; ++j) {
            unsigned ws = 0;
            for (int b = 0; b < 9; ++b)
                ws |= ((rAll[k][j] >> posAll[k][b]) & 1u) << b;
            K.P[k].w[j] = (unsigned short)ws;
        }
    }
    for (int b = 0; b < 9; ++b) K.Gcol0[b] = (unsigned short)(1u << posAll[0][b]);
    for (int s = 0; s < 8; ++s) K.vc0[s] = (unsigned short)vcAll[0][s];
    for (int q = 0; q < NQ; ++q) {
        unsigned ws = 0;
        for (int b = 0; b < 9; ++b)
            ws |= ((rfin[q] >> posAll[NPASS - 1][b]) & 1u) << b;
        K.wq[q] = (unsigned short)ws;
        unsigned tb = 0;
        for (int s = 0; s < 8; ++s)
            tb |= (unsigned)(pc(rfin[q] & vcAll[NPASS - 1][s]) & 1) << s;
        K.tab[q] = (unsigned char)tb;
    }

    int nblk = (B + 1) / 2;
    qsim_k<<<nblk, TPB, 0, stream>>>(x, qp, fc_w, fc_b, out, B, K);
}

// Round 8
// 262.591 us; speedup vs baseline: 1.3507x; 1.3382x over previous
//
#include <hip/hip_runtime.h>

#define NQ 12
#define NL 6
#define NC 10
#define DIM 4096
#define TPB 512
#define NPASS 24

typedef float v2f __attribute__((ext_vector_type(2)));
#define FMA2(a, b, c) __builtin_elementwise_fma((a), (b), (c))

__device__ __forceinline__ v2f splat2(float v) { v2f r; r.x = v; r.y = v; return r; }

// VOP3P packed-f32, coefficient broadcast via op_sel (proven to assemble+run in r6).
// P is a v2f coefficient pair; _L broadcasts its lo 32b to both halves, _H its hi 32b.
#define PKMUL_L(d, P, B) asm("v_pk_mul_f32 %0, %1, %2 op_sel:[0,0] op_sel_hi:[0,1]" : "=v"(d) : "v"(P), "v"(B))
#define PKMUL_H(d, P, B) asm("v_pk_mul_f32 %0, %1, %2 op_sel:[1,0] op_sel_hi:[1,1]" : "=v"(d) : "v"(P), "v"(B))
#define PKFMA_L(d, P, B, C) asm("v_pk_fma_f32 %0, %1, %2, %3 op_sel:[0,0,0] op_sel_hi:[0,1,1]" : "=v"(d) : "v"(P), "v"(B), "v"(C))
#define PKFMA_H(d, P, B, C) asm("v_pk_fma_f32 %0, %1, %2, %3 op_sel:[1,0,0] op_sel_hi:[1,1,1]" : "=v"(d) : "v"(P), "v"(B), "v"(C))

struct PassA { unsigned short Acol[9]; unsigned short svo4[8]; unsigned short w[3]; };
struct QCArgs {
    PassA P[NPASS];
    unsigned short Gcol0[9];
    unsigned short vc0[8];
    unsigned short wq[NQ];
    unsigned char  tab[NQ];
};

__global__ __launch_bounds__(TPB, 4) void qsim_k(
    const float* __restrict__ x, const float* __restrict__ qp,
    const float* __restrict__ fcw, const float* __restrict__ fcb,
    float* __restrict__ out, int B, QCArgs K)
{
    __shared__ float4 stv[DIM];          // (re.b0, re.b1, im.b0, im.b1), layout T*m
    __shared__ float4 gmat[NL * NQ];     // (ur, ui, wr, wi)
    __shared__ v2f csn[NQ], snn[NQ];
    __shared__ v2f zred[8 * NQ];
    __shared__ v2f zfin[NQ];

    const unsigned tid = threadIdx.x;
    const int blk = blockIdx.x;
    const int b0 = blk * 2;
    const int b1 = blk * 2 + 1;

    if (tid < NL * NQ) {
        float phi = qp[tid * 3 + 0];
        float th  = qp[tid * 3 + 1];
        float om  = qp[tid * 3 + 2];
        float st_, ct, sa, ca, sb, cb;
        sincosf(0.5f * th, &st_, &ct);
        sincosf(0.5f * (phi + om), &sa, &ca);
        sincosf(0.5f * (phi - om), &sb, &cb);
        gmat[tid] = make_float4(ca * ct, -sa * ct, cb * st_, -sb * st_);
    }
    if (tid < 2 * NQ) {
        int half = tid / NQ;
        int q = tid - half * NQ;
        int bb = blk * 2 + half;
        float xx = (bb < B) ? x[bb * NQ + q] : 0.0f;
        float s, c;
        sincosf(0.5f * xx, &s, &c);
        if (half == 0) { csn[q].x = c; snn[q].x = s; }
        else           { csn[q].y = c; snn[q].y = s; }
    }
    __syncthreads();

    // ---- init product state PRE-LOOP (writes via pass-0 map); bit p of m <-> qubit 11-p ----
    {
        unsigned G = 0, A0 = 0;
        #pragma unroll
        for (int b2 = 0; b2 < 9; ++b2) {
            unsigned mneg = (unsigned)(-(int)((tid >> b2) & 1u));
            G  ^= mneg & (unsigned)K.Gcol0[b2];
            A0 ^= mneg & (unsigned)K.P[0].Acol[b2];
        }
        #pragma unroll
        for (int s = 0; s < 8; ++s) {
            unsigned idx = G ^ (unsigned)K.vc0[s];
            v2f amp = splat2(1.0f);
            #pragma unroll
            for (int p = 0; p < 12; ++p)
                amp *= ((idx >> p) & 1) ? snn[11 - p] : csn[11 - p];
            unsigned ad0 = A0 ^ (unsigned)K.P[0].svo4[s];
            *(float4*)((char*)stv + ad0) = make_float4(amp.x, amp.y, 0.0f, 0.0f);
        }
    }

    v2f aR[8], aI[8];

    // ---- 24 passes, 3 gates each; in-place per-thread cosets; 1 barrier/pass ----
    #pragma unroll 1
    for (int k = 0; k < NPASS; ++k) {
        __syncthreads();
        const PassA& P = K.P[k];

        unsigned A = 0;
        #pragma unroll
        for (int b2 = 0; b2 < 9; ++b2) {
            unsigned mneg = (unsigned)(-(int)((tid >> b2) & 1u));
            A ^= mneg & (unsigned)P.Acol[b2];
        }
        unsigned ad[8];
        #pragma unroll
        for (int s = 0; s < 8; ++s) {
            ad[s] = A ^ (unsigned)P.svo4[s];
            float4 f4 = *(const float4*)((const char*)stv + ad[s]);
            aR[s].x = f4.x; aR[s].y = f4.y;
            aI[s].x = f4.z; aI[s].y = f4.w;
        }

        const int gb = (k >> 2) * NQ + (k & 3) * 3;
        #pragma unroll
        for (int j = 0; j < 3; ++j) {
            float4 gq = gmat[gb + j];
            unsigned sg = (unsigned)(__popc((unsigned)P.w[j] & tid) & 1) << 31;
            v2f P1, P1n, P2, P2n;
            P1.x  = gq.x;
            P1.y  = __uint_as_float(__float_as_uint(gq.y) ^ sg);
            P1n.x = gq.x;
            P1n.y = __uint_as_float(__float_as_uint(P1.y) ^ 0x80000000u);
            P2.x  = __uint_as_float(__float_as_uint(gq.z) ^ sg);
            P2.y  = gq.w;
            P2n.x = __uint_as_float(__float_as_uint(P2.x) ^ 0x80000000u);
            P2n.y = __uint_as_float(__float_as_uint(gq.w) ^ 0x80000000u);
            #pragma unroll
            for (int s = 0; s < 8; ++s) {
                if (!(s & (1 << j))) {
                    const int sb = s | (1 << j);
                    v2f a0r = aR[s], a0i = aI[s], a1r = aR[sb], a1i = aI[sb];
                    v2f t, o;
                    // o0r = ur*a0r - u1*a0i - w1*a1r - wi*a1i
                    PKMUL_H(t, P2n, a1i); PKFMA_L(t, P2n, a1r, t); PKFMA_H(t, P1n, a0i, t); PKFMA_L(o, P1, a0r, t); aR[s] = o;
                    // o0i = ur*a0i + u1*a0r - w1*a1i + wi*a1r
                    PKMUL_H(t, P2, a1r);  PKFMA_L(t, P2n, a1i, t); PKFMA_H(t, P1, a0r, t);  PKFMA_L(o, P1, a0i, t); aI[s] = o;
                    // o1r = ur*a1r + u1*a1i + w1*a0r - wi*a0i
                    PKMUL_H(t, P2n, a0i); PKFMA_L(t, P2, a0r, t);  PKFMA_H(t, P1, a1i, t);  PKFMA_L(o, P1, a1r, t); aR[sb] = o;
                    // o1i = ur*a1i - u1*a1r + w1*a0i + wi*a0r
                    PKMUL_H(t, P2, a0r);  PKFMA_L(t, P2, a0i, t);  PKFMA_H(t, P1n, a1r, t); PKFMA_L(o, P1, a1i, t); aI[sb] = o;
                }
            }
        }

        if (k < NPASS - 1) {
            #pragma unroll
            for (int s = 0; s < 8; ++s)
                *(float4*)((char*)stv + ad[s]) =
                    make_float4(aR[s].x, aR[s].y, aI[s].x, aI[s].y);
        }
    }

    // ---- PauliZ expvals from final-pass registers ----
    v2f p2[8];
    #pragma unroll
    for (int s = 0; s < 8; ++s) p2[s] = FMA2(aR[s], aR[s], aI[s] * aI[s]);

    v2f z[NQ];
    #pragma unroll
    for (int q = 0; q < NQ; ++q) {
        float base = (__popc((unsigned)K.wq[q] & tid) & 1) ? -1.0f : 1.0f;
        v2f acc = splat2(0.0f);
        #pragma unroll
        for (int s = 0; s < 8; ++s) {
            float sgn = ((K.tab[q] >> s) & 1) ? -base : base;
            acc = FMA2(splat2(sgn), p2[s], acc);
        }
        z[q] = acc;
    }

    #pragma unroll
    for (int q = 0; q < NQ; ++q) {
        float vx = z[q].x, vy = z[q].y;
        #pragma unroll
        for (int o = 1; o < 64; o <<= 1) {
            vx += __shfl_xor(vx, o, 64);
            vy += __shfl_xor(vy, o, 64);
        }
        z[q].x = vx; z[q].y = vy;
    }
    const int lane = tid & 63, wv = tid >> 6;
    if (lane == 0) {
        #pragma unroll
        for (int q = 0; q < NQ; ++q) zred[wv * NQ + q] = z[q];
    }
    __syncthreads();
    if (tid < NQ) {
        v2f acc = zred[tid];
        #pragma unroll
        for (int w2 = 1; w2 < 8; ++w2) acc += zred[w2 * NQ + tid];
        zfin[tid] = acc;
    }
    __syncthreads();

    if (tid < NC) {
        v2f acc = splat2(fcb[tid]);
        #pragma unroll
        for (int q = 0; q < NQ; ++q) acc = FMA2(splat2(fcw[tid * NQ + q]), zfin[q], acc);
        out[b0 * NC + tid] = acc.x;
        if (b1 < B) out[b1 * NC + tid] = acc.y;
    }
}

// ---------------- host: GF(2) circuit algebra + per-8-lane conflict-free layout ----------------
static void inv12(const unsigned Ain[12], unsigned Ai[12]) {
    unsigned M[12], I[12];
    for (int i = 0; i < 12; ++i) { M[i] = Ain[i]; I[i] = 1u << i; }
    for (int c = 0; c < 12; ++c) {
        int pr = -1;
        for (int r2 = c; r2 < 12; ++r2) if ((M[r2] >> c) & 1u) { pr = r2; break; }
        unsigned tm = M[c]; M[c] = M[pr]; M[pr] = tm;
        tm = I[c]; I[c] = I[pr]; I[pr] = tm;
        for (int r2 = 0; r2 < 12; ++r2)
            if (r2 != c && ((M[r2] >> c) & 1u)) { M[r2] ^= M[c]; I[r2] ^= I[c]; }
    }
    for (int i = 0; i < 12; ++i) Ai[i] = I[i];
}

static unsigned lcg(unsigned& s) { s = s * 1664525u + 1013904223u; return s >> 8; }
static int pc(unsigned v) { return __builtin_popcount(v); }

static int rank_rows(const unsigned* rows, int n) {
    unsigned ech[16], low[16]; int rk = 0;
    for (int i = 0; i < n; ++i) {
        unsigned v = rows[i];
        for (int k2 = 0; k2 < rk; ++k2) if (v & low[k2]) v ^= ech[k2];
        if (v) { ech[rk] = v; low[rk] = v & (0u - v); ++rk; }
    }
    return rk;
}

extern "C" void kernel_launch(void* const* d_in, const int* in_sizes, int n_in,
                              void* d_out, int out_size, void* d_ws, size_t ws_size,
                              hipStream_t stream) {
    const float* x    = (const float*)d_in[0];
    const float* qp   = (const float*)d_in[1];
    const float* fc_w = (const float*)d_in[2];
    const float* fc_b = (const float*)d_in[3];
    float* out = (float*)d_out;
    int B = in_sizes[0] / NQ;

    unsigned L[12];
    for (int i = 0; i < 12; ++i) L[i] = 1u << i;

    static unsigned vAll[NPASS][3], rAll[NPASS][3], vcAll[NPASS][8];
    static int posAll[NPASS][9];

    for (int l = 0; l < NL; ++l) {
        unsigned Linv[12];
        inv12(L, Linv);
        for (int m = 0; m < 4; ++m) {
            int k = l * 4 + m;
            for (int j = 0; j < 3; ++j) {
                int q = 3 * m + j, bb = 11 - q;
                rAll[k][j] = L[bb];
                unsigned vv = 0;
                for (int i = 0; i < 12; ++i) vv |= ((Linv[i] >> bb) & 1u) << i;
                vAll[k][j] = vv;
            }
            unsigned w[3] = { vAll[k][0], vAll[k][1], vAll[k][2] };
            int piv[3];
            for (int j = 0; j < 3; ++j) {
                for (int k2 = 0; k2 < j; ++k2)
                    if ((w[j] >> piv[k2]) & 1u) w[j] ^= w[k2];
                piv[j] = __builtin_ctz(w[j]);
            }
            bool ispiv[12] = {};
            for (int j = 0; j < 3; ++j) ispiv[piv[j]] = true;
            int c = 0;
            for (int pos = 0; pos < 12; ++pos)
                if (!ispiv[pos]) posAll[k][c++] = pos;
            for (int s = 0; s < 8; ++s) {
                unsigned vc = 0;
                for (int j = 0; j < 3; ++j) if ((s >> j) & 1) vc ^= vAll[k][j];
                vcAll[k][s] = vc;
            }
        }
        int rr = l + 1;
        for (int q = 0; q < 12; ++q) {
            int tq = (q + rr) % 12;
            L[11 - tq] ^= L[11 - q];
        }
    }
    unsigned rfin[12];
    for (int q = 0; q < 12; ++q) rfin[q] = L[11 - q];

    // ---- label search: nonzero 3-bit label per position; every pass's 9 positions must span GF(2)^3 ----
    unsigned labels[12];
    unsigned seed = 0xC0FFEE1u;
    bool okL = false;
    for (int att = 0; att < 300000 && !okL; ++att) {
        for (int i = 0; i < 12; ++i) labels[i] = 1u + (lcg(seed) % 7u);
        okL = true;
        for (int k = 0; k < NPASS && okL; ++k) {
            unsigned vals[9];
            for (int b = 0; b < 9; ++b) vals[b] = labels[posAll[k][b]];
            okL = (rank_rows(vals, 9) >= 3);
        }
    }

    // ---- per-pass: move an independent-label triple to thread bits 0..2 ----
    for (int k = 0; k < NPASS; ++k) {
        int used[9] = {};
        int chosen[3]; int nch = 0;
        unsigned ech[3], low[3]; int rk = 0;
        for (int b = 0; b < 9 && nch < 3; ++b) {
            unsigned v = labels[posAll[k][b]];
            for (int j = 0; j < rk; ++j) if (v & low[j]) v ^= ech[j];
            if (v) { ech[rk] = v; low[rk] = v & (0u - v); ++rk; chosen[nch++] = b; used[b] = 1; }
        }
        for (int b = 0; b < 9 && nch < 3; ++b)
            if (!used[b]) { chosen[nch++] = b; used[b] = 1; }
        int outp[9]; int c2 = 0;
        for (int j = 0; j < nch; ++j) outp[c2++] = posAll[k][chosen[j]];
        for (int b = 0; b < 9; ++b) if (!used[b]) outp[c2++] = posAll[k][b];
        for (int b = 0; b < 9; ++b) posAll[k][b] = outp[b];
    }

    // ---- layout matrix T: rows 0..2 from labels, extend to full rank ----
    unsigned Trow[12];
    for (int i = 0; i < 3; ++i) {
        unsigned r = 0;
        for (int pos = 0; pos < 12; ++pos) r |= ((labels[pos] >> i) & 1u) << pos;
        Trow[i] = r;
    }
    {
        unsigned ech[12], low[12]; int rk = 0;
        auto addrow = [&](unsigned vr) -> bool {
            unsigned vv = vr;
            for (int i = 0; i < rk; ++i) if (vv & low[i]) vv ^= ech[i];
            if (!vv) return false;
            ech[rk] = vv; low[rk] = vv & (0u - vv); ++rk;
            return true;
        };
        addrow(Trow[0]); addrow(Trow[1]); addrow(Trow[2]);
        int idx = 3, tries = 0;
        while (idx < 12 && tries < 100000) {
            unsigned rr2 = lcg(seed) & 4095u;
            if (rr2 && addrow(rr2)) Trow[idx++] = rr2;
            ++tries;
        }
        for (int i = 0; i < 12 && idx < 12; ++i)
            if (addrow(1u << i)) Trow[idx++] = 1u << i;
    }
    unsigned Tcol[12];
    for (int pos = 0; pos < 12; ++pos) {
        unsigned o = 0;
        for (int i = 0; i < 12; ++i) o |= ((Trow[i] >> pos) & 1u) << i;
        Tcol[pos] = o;
    }
    auto Tmap = [&](unsigned m) -> unsigned {
        unsigned o = 0;
        for (int i = 0; i < 12; ++i) o |= (unsigned)(pc(Trow[i] & m) & 1) << i;
        return o;
    };

    QCArgs K;
    for (int k = 0; k < NPASS; ++k) {
        for (int b = 0; b < 9; ++b)
            K.P[k].Acol[b] = (unsigned short)(Tcol[posAll[k][b]] << 4);
        for (int s = 0; s < 8; ++s)
            K.P[k].svo4[s] = (unsigned short)(Tmap(vcAll[k][s]) << 4);
        for (int j = 0; j < 3; ++j) {
            unsigned ws = 0;
            for (int b = 0; b < 9; ++b)
                ws |= ((rAll[k][j] >> posAll[k][b]) & 1u) << b;
            K.P[k].w[j] = (unsigned short)ws;
        }
    }
    for (int b = 0; b < 9; ++b) K.Gcol0[b] = (unsigned short)(1u << posAll[0][b]);
    for (int s = 0; s < 8; ++s) K.vc0[s] = (unsigned short)vcAll[0][s];
    for (int q = 0; q < NQ; ++q) {
        unsigned ws = 0;
        for (int b = 0; b < 9; ++b)
            ws |= ((rfin[q] >> posAll[NPASS - 1][b]) & 1u) << b;
        K.wq[q] = (unsigned short)ws;
        unsigned tb = 0;
        for (int s = 0; s < 8; ++s)
            tb |= (unsigned)(pc(rfin[q] & vcAll[NPASS - 1][s]) & 1) << s;
        K.tab[q] = (unsigned char)tb;
    }

    int nblk = (B + 1) / 2;
    qsim_k<<<nblk, TPB, 0, stream>>>(x, qp, fc_w, fc_b, out, B, K);
}